// Round 12
// baseline (107.145 us; speedup 1.0000x reference)
//
#include <hip/hip_runtime.h>
#include <hip/hip_bf16.h>

#define SCOPE 63
#define BLOCK_THREADS 64
#define ROWS_PER_BLOCK 32
#define TILE_ELEMS (ROWS_PER_BLOCK * SCOPE)   // 2016 floats = 8064 B
#define NOUT 32                                // outputs per lane (half-row)

// ---------------------------------------------------------------------------
// Kernel 1: inverse filter g = IFFT( 1 / FFT(delta - f) ) in fp64. Negligible.
// ---------------------------------------------------------------------------
__global__ void compute_inverse_filter(const float* __restrict__ f,
                                       float* __restrict__ g) {
    __shared__ double hre[SCOPE];
    __shared__ double him[SCOPE];
    const double TWO_PI = 6.283185307179586476925286766559;
    int t = threadIdx.x;
    if (t < SCOPE) {
        double re = 0.0, im = 0.0;
        for (int n = 0; n < SCOPE; ++n) {
            double x = (n == 0 ? 1.0 : 0.0) - (double)f[n];
            double ang = -TWO_PI * (double)(t * n) / (double)SCOPE;
            re += x * cos(ang);
            im += x * sin(ang);
        }
        double d = re * re + im * im;
        hre[t] = re / d;
        him[t] = -im / d;
    }
    __syncthreads();
    if (t < SCOPE) {
        double acc = 0.0;
        for (int k = 0; k < SCOPE; ++k) {
            double ang = TWO_PI * (double)(k * t) / (double)SCOPE;
            acc += hre[k] * cos(ang) - him[k] * sin(ang);
        }
        g[t] = (float)(acc / (double)SCOPE);
    }
}

// ---------------------------------------------------------------------------
// Compile-time-unrolled helpers (static indices only -> SROA to registers).
// ---------------------------------------------------------------------------
// d[J0..J1] = p[0..J1-J0]  (static immediate offsets from a runtime pointer)
template <int J0, int J1, int J>
struct LoadSegR {
    __device__ static inline void run(float (&d)[SCOPE], const float* p) {
        LoadSegR<J0, J1, J - 1>::run(d, p);
        d[J] = p[J - J0];
    }
};
template <int J0, int J1>
struct LoadSegR<J0, J1, -1000> {};  // unused
template <int J0, int J1>
__device__ inline void LoadSeg(float (&d)[SCOPE], const float* p);
template <int J0, int J1, int J>
struct LoadSegImpl {
    __device__ static inline void run(float (&d)[SCOPE], const float* p) {
        LoadSegImpl<J0, J1, J - 1>::run(d, p);
        d[J] = p[J - J0];
    }
};
template <int J0, int J1>
struct LoadSegImpl<J0, J1, -1> {
    __device__ static inline void run(float (&)[SCOPE], const float*) {}
};
// specialization anchor: stop below J0
#define LOADSEG(d, p, J0, J1) LoadSegStop<J0, J1>::run(d, p)
template <int J0, int J1>
struct LoadSegStop {
    template <int J>
    struct Step {
        __device__ static inline void run(float (&d)[SCOPE], const float* p) {
            if constexpr (J >= J0) {
                Step<J - 1>::run(d, p);
                d[J] = p[J - J0];
            }
        }
    };
    __device__ static inline void run(float (&d)[SCOPE], const float* p) {
        Step<J1>::run(d, p);
    }
};

// FMA tap M: acc[i] += gm * a[(i - M) mod 63], i = 0..NOUT-1
template <int M, int I>
struct TapRow {
    __device__ static inline void run(float (&acc)[NOUT], const float (&a)[SCOPE],
                                      float gm) {
        TapRow<M, I - 1>::run(acc, a, gm);
        acc[I] += gm * a[(I - M + SCOPE) % SCOPE];
    }
};
template <int M>
struct TapRow<M, -1> {
    __device__ static inline void run(float (&)[NOUT], const float (&)[SCOPE], float) {}
};

// Loop over taps M = 0..62; g[M] is a uniform LDS broadcast read.
template <int M>
struct TapLoop {
    __device__ static inline void run(float (&acc)[NOUT], const float (&a)[SCOPE],
                                      const float* gs) {
        TapLoop<M - 1>::run(acc, a, gs);
        const float gm = gs[M];
        TapRow<M, NOUT - 1>::run(acc, a, gm);
    }
};
template <>
struct TapLoop<0> {   // M = 0 initializes the accumulators
    __device__ static inline void run(float (&acc)[NOUT], const float (&a)[SCOPE],
                                      const float* gs) {
        const float g0 = gs[0];
#pragma unroll
        for (int i = 0; i < NOUT; ++i) acc[i] = g0 * a[i];
    }
};

// Store acc[0..30] to q1[0..30] (static offsets); acc[31] guarded by caller.
template <int I>
struct StoreSeg {
    __device__ static inline void run(float* q1, const float (&acc)[NOUT]) {
        StoreSeg<I - 1>::run(q1, acc);
        q1[I] = acc[I];
    }
};
template <>
struct StoreSeg<-1> {
    __device__ static inline void run(float*, const float (&)[NOUT]) {}
};

// ---------------------------------------------------------------------------
// Kernel 2: per-row circular convolution, 32 rows/block, 2 lanes per row.
// Lane = 2r + h: computes outputs n = 32h .. 32h+31 of row r (h=1: 31 outs).
// Row is loaded ROTATED by 32h so register indexing stays compile-time:
//   a_rot[k] = row[(32h + k) mod 63]
//   out[32h + i] = sum_m g[m] * a_rot[(i - m) mod 63]
// Rotation needs only 2 runtime base pointers with static immediate offsets:
//   j in [0,31):  a[j] = (row + 32h)[j]
//   j in [31,63): a[j] = (row + 31 - 31h)[j - 31]
// Working set: a[63] + acc[32] + few ~= 105 VGPR; LDS 8.3 KB -> ~16 blocks/CU
// = 4 waves/SIMD (2.5x round-11 residency), per-wave work halved.
// ---------------------------------------------------------------------------
__global__ void __launch_bounds__(BLOCK_THREADS)
circ_conv_kernel(const float* __restrict__ A,
                 const float* __restrict__ G,
                 float* __restrict__ O) {
    __shared__ __align__(16) float tile[TILE_ELEMS];
    __shared__ float gs[SCOPE];

    const int lane = threadIdx.x;       // 1 wave per block
    const int r    = lane >> 1;         // row within tile
    const int h    = lane & 1;          // output half

    const long long row0 = (long long)blockIdx.x * ROWS_PER_BLOCK;
    const float* __restrict__ src = A + row0 * SCOPE;
    float* __restrict__ dst       = O + row0 * SCOPE;

    if (lane < SCOPE) gs[lane] = G[lane];

    // ---- stage 32 rows (2016 floats = 504 float4) into LDS, coalesced ----
    const float4* src4 = (const float4*)src;
    float4* w4 = (float4*)tile;
#pragma unroll
    for (int it = 0; it < 7; ++it)
        w4[it * 64 + lane] = src4[it * 64 + lane];
    if (lane < 56)
        w4[448 + lane] = src4[448 + lane];

    __syncthreads();

    // ---- rotated row load: 2 runtime bases, all-static offsets ----
    float* myrow = tile + r * SCOPE;
    const float* q1 = myrow + 32 * h;        // j in [0,31)
    const float* q2 = myrow + 31 - 31 * h;   // j in [31,63)
    float a[SCOPE];
    LoadSegStop<0, 30>::run(a, q1);
    LoadSegStop<31, 62>::run(a, q2);

    // ---- 63-tap convolution into 32 register accumulators ----
    float acc[NOUT];
    TapLoop<SCOPE - 1>::run(acc, a, gs);

    // ---- write outputs back to own row region (2-way bank alias = free) ----
    float* qo = myrow + 32 * h;
    StoreSeg<30>::run(qo, acc);
    if (h == 0) qo[31] = acc[31];   // half 1 has only 31 outputs

    __syncthreads();

    // ---- coalesced store ----
    float4* dst4 = (float4*)dst;
#pragma unroll
    for (int it = 0; it < 7; ++it)
        dst4[it * 64 + lane] = w4[it * 64 + lane];
    if (lane < 56)
        dst4[448 + lane] = w4[448 + lane];
}

// ---------------------------------------------------------------------------
extern "C" void kernel_launch(void* const* d_in, const int* in_sizes, int n_in,
                              void* d_out, int out_size, void* d_ws, size_t ws_size,
                              hipStream_t stream) {
    const float* activations = (const float*)d_in[0];
    const float* filt        = (const float*)d_in[1];
    float* out               = (float*)d_out;
    float* g                 = (float*)d_ws;   // 63 floats of scratch

    hipLaunchKernelGGL(compute_inverse_filter, dim3(1), dim3(64), 0, stream,
                       filt, g);

    const long long total = (long long)in_sizes[0];
    const long long rows  = total / SCOPE;                 // 524288
    const int blocks      = (int)(rows / ROWS_PER_BLOCK);  // 16384, exact

    hipLaunchKernelGGL(circ_conv_kernel, dim3(blocks), dim3(BLOCK_THREADS), 0,
                       stream, activations, g, out);
}